// Round 11
// baseline (1087803.613 us; speedup 1.0000x reference)
//
#include <hip/hip_runtime.h>
#include <stdint.h>

typedef __attribute__((ext_vector_type(8))) short short8;
typedef __attribute__((ext_vector_type(4))) short short4_;
typedef __attribute__((ext_vector_type(4))) float f4;
typedef __attribute__((ext_vector_type(4))) uint32_t u32x4;

#define B_ 64
#define T_ 512
#define E_ 512
#define H_ 512
#define GH 2048  // 4*H

static __device__ __forceinline__ uint16_t f2bf(float f) {
  uint32_t u = __builtin_bit_cast(uint32_t, f);
  uint32_t r = (u + 0x7FFFu + ((u >> 16) & 1u)) >> 16;
  return (uint16_t)r;
}
static __device__ __forceinline__ float bf2f(uint16_t b) {
  return __builtin_bit_cast(float, (uint32_t)b << 16);
}
static __device__ __forceinline__ float sigmoidf_(float x) {
  return 1.0f / (1.0f + __expf(-x));
}
static __device__ __forceinline__ float tanhf_(float x) {
  float e = __expf(-2.0f * fabsf(x));
  float t = (1.0f - e) / (1.0f + e);
  return __builtin_copysignf(t, x);
}

// ---- XCD-local L2-coherent access helpers: sc0 = bypass L1, coherence at the
// XCD's L2. Valid ONLY because each bg's producers+consumers are pinned to one
// XCD (claim scheme below). Protocol ordering identical to r5/r9-proven:
// producer stores -> vmcnt(0) drain -> barrier -> flag; consumer: poll -> load.
// Rule (r8): a load whose value is consumed must have its s_waitcnt INSIDE the
// same asm block, or be covered by vmcnt(0)+sched_barrier+retie.
static __device__ __forceinline__ u32x4 ld_flag4_l2(const int* p) {
  u32x4 v;
  asm volatile("global_load_dwordx4 %0, %1, off sc0\n\ts_waitcnt vmcnt(0)"
               : "=v"(v) : "v"(p) : "memory");
  return v;
}
static __device__ __forceinline__ void ld_x4_l2(u32x4* d, const void* p) {
  asm volatile("global_load_dwordx4 %0, %1, off sc0" : "=v"(*d) : "v"(p));
}
static __device__ __forceinline__ void st_u32_l2(uint32_t* p, uint32_t v) {
  asm volatile("global_store_dword %0, %1, off sc0" :: "v"(p), "v"(v) : "memory");
}
static __device__ __forceinline__ void st_flag_l2(int* p, int v) {
  asm volatile("global_store_dword %0, %1, off sc0" :: "v"(p), "v"(v) : "memory");
}

// ---------------- prep: split W_hh fp32 -> bf16 hi + bf16 lo
__global__ void k_prep(const float* __restrict__ Whh, uint16_t* __restrict__ Whi_g,
                       uint16_t* __restrict__ Wlo_g) {
  int i = blockIdx.x * 256 + threadIdx.x;
  float w = Whh[i];
  uint16_t hi = f2bf(w);
  Whi_g[i] = hi;
  Wlo_g[i] = f2bf(w - bf2f(hi));
}

// ---------------- init: h0 -> packed (hi | lo<<16) parity-0 buffer; zero flags
// AND claim counters (flags[192..195]) — re-zeroed every launch/replay.
__global__ void k_init(const float* __restrict__ h0, uint32_t* __restrict__ hP0,
                       int* __restrict__ flags) {
  int i = blockIdx.x * 256 + threadIdx.x;
  if (i < B_ * H_) {
    float v = h0[i];
    uint16_t hi = f2bf(v);
    uint16_t lo = f2bf(v - bf2f(hi));
    hP0[i] = (uint32_t)hi | ((uint32_t)lo << 16);
  }
  if (i < 256) flags[i] = 0;
}

// ---------------- pre-projection GEMM (verified r1-r10). Output: per-consumer
// blocks pre2[((t_rel*32+ug)*4+bg)*1024 + g_loc*16 + b_loc], g_loc = q*16+u_loc.
// Epilogue stores NONTEMPORAL (read-once stream; keep caches clean).
__launch_bounds__(256)
__global__ void k_pre(const int* __restrict__ x, const float* __restrict__ emb,
                      const float* __restrict__ Wih, const float* __restrict__ bih,
                      const float* __restrict__ bhh, float* __restrict__ pre2, int t0) {
  __shared__ uint16_t As[128 * 64];
  __shared__ uint16_t Bs[128 * 64];
  const int tid = threadIdx.x;
  const int tm = blockIdx.x >> 4;
  const int tn = blockIdx.x & 15;
  const int wid = tid >> 6, lane = tid & 63;
  const int wr = wid >> 1, wc = wid & 1;

  const int arow = tid >> 1;
  const int half = tid & 1;
  const int m = tm * 128 + arow;
  const int bb = m & 63;
  const int tt = t0 + (m >> 6);
  const int xid = x[bb * T_ + tt];
  const float* asrc = emb + (size_t)xid * E_ + half * 32;
  const float* bsrc = Wih + (size_t)(tn * 128 + arow) * E_ + half * 32;

  f4 acc[4][4];
#pragma unroll
  for (int a = 0; a < 4; ++a)
#pragma unroll
    for (int b = 0; b < 4; ++b) acc[a][b] = (f4){0.f, 0.f, 0.f, 0.f};

  for (int kk = 0; kk < 8; ++kk) {
    __syncthreads();
#pragma unroll
    for (int gi = 0; gi < 4; ++gi) {
      f4 a0 = *(const f4*)(asrc + kk * 64 + gi * 8);
      f4 a1 = *(const f4*)(asrc + kk * 64 + gi * 8 + 4);
      f4 b0 = *(const f4*)(bsrc + kk * 64 + gi * 8);
      f4 b1 = *(const f4*)(bsrc + kk * 64 + gi * 8 + 4);
      short8 va, vb;
#pragma unroll
      for (int j = 0; j < 4; ++j) {
        va[j] = (short)f2bf(a0[j]); va[4 + j] = (short)f2bf(a1[j]);
        vb[j] = (short)f2bf(b0[j]); vb[4 + j] = (short)f2bf(b1[j]);
      }
      int kq = half * 4 + gi;
      *(short8*)(As + arow * 64 + (kq ^ (arow & 7)) * 8) = va;
      *(short8*)(Bs + arow * 64 + (kq ^ (arow & 7)) * 8) = vb;
    }
    __syncthreads();
#pragma unroll
    for (int ks = 0; ks < 2; ++ks) {
      short8 af[4], bfr[4];
#pragma unroll
      for (int mi = 0; mi < 4; ++mi) {
        int row = wr * 64 + mi * 16 + (lane & 15);
        int kq = ks * 4 + (lane >> 4);
        af[mi] = *(const short8*)(As + row * 64 + (kq ^ (row & 7)) * 8);
      }
#pragma unroll
      for (int ni = 0; ni < 4; ++ni) {
        int row = wc * 64 + ni * 16 + (lane & 15);
        int kq = ks * 4 + (lane >> 4);
        bfr[ni] = *(const short8*)(Bs + row * 64 + (kq ^ (row & 7)) * 8);
      }
#pragma unroll
      for (int mi = 0; mi < 4; ++mi)
#pragma unroll
        for (int ni = 0; ni < 4; ++ni)
          acc[mi][ni] = __builtin_amdgcn_mfma_f32_16x16x32_bf16(af[mi], bfr[ni], acc[mi][ni], 0, 0, 0);
    }
  }
#pragma unroll
  for (int ni = 0; ni < 4; ++ni) {
    int n = tn * 128 + wc * 64 + ni * 16 + (lane & 15);
    float bias = bih[n] + bhh[n];
    int q = n >> 9, u = n & 511;
    int ug = u >> 4, uloc = u & 15;
    int gl = q * 16 + uloc;
#pragma unroll
    for (int mi = 0; mi < 4; ++mi) {
      int mrow = tm * 128 + wr * 64 + mi * 16 + (lane >> 4) * 4;
      int trel = mrow >> 6;
      int bbr = mrow & 63;
      f4 vst;
#pragma unroll
      for (int j = 0; j < 4; ++j) vst[j] = acc[mi][ni][j] + bias;
      float* dst = pre2 + (((size_t)trel * 32 + ug) * 4 + (bbr >> 4)) * 1024 + gl * 16 + (bbr & 15);
      __builtin_nontemporal_store(vst, (f4*)dst);
    }
  }
}

// ---------------- persistent recurrence, XCD-pinned L2 coherence.
// grid=256, 160 KiB LDS -> 1 wg/CU capacity-exact: every XCD hosts exactly 32
// wgs. bg = XCC_ID (XCDs 0-3; 4-7 exit), ug = claimed slot 0..31. All h/flag
// traffic via sc0 at the XCD's L2 (~250cy RT vs ~800 at L3). Protocol ordering,
// staging math, MFMA, gate combine byte-identical to r9/r10-verified. Polls
// BOUNDED: any placement/XCC assumption failure => fast absmax error, no wedge.
__launch_bounds__(256)
__global__ void k_lstm(const float* __restrict__ pre2, const uint16_t* __restrict__ Whi_g,
                       const uint16_t* __restrict__ Wlo_g, const float* __restrict__ c0,
                       float* __restrict__ out, uint32_t* __restrict__ hP0,
                       uint32_t* __restrict__ hP1, float* __restrict__ c_state,
                       int* __restrict__ flags, int t0, int TB) {
  extern __shared__ char smem[];
  uint16_t* WhiL = (uint16_t*)smem;              // [64][512] 64 KiB
  uint16_t* WloL = (uint16_t*)(smem + 65536);    // [64][512] 64 KiB
  uint16_t* Hh   = (uint16_t*)(smem + 131072);   // [16][512] 16 KiB
  uint16_t* Hl   = (uint16_t*)(smem + 147456);   // [16][512] 16 KiB

  const int tid = threadIdx.x;

  // ---- XCD claim: bg = XCC_ID, ug = slot from per-XCD counter.
  uint32_t xcc;
  asm volatile("s_getreg_b32 %0, hwreg(HW_REG_XCC_ID)" : "=s"(xcc));
  const int xcd = (int)(xcc & 0xF);
  if (tid == 0) {
    int sl = 999;
    if (xcd < 4) sl = atomicAdd(flags + 192 + xcd, 1);  // device-scope claim
    *(int*)smem = sl;
  }
  __syncthreads();
  const int slot = *(const int*)smem;
  __syncthreads();
  if (slot >= 32) return;  // XCDs 4-7 and any overflow exit (frees nothing needed)
  const int bg = xcd;      // batch group (16 rows)
  const int ug = slot;     // unit group (16 units)

  const int wv = tid >> 6, lane = tid & 63;
  const int wi = lane & 15, hi4 = lane >> 4;
  const int q = wi & 3, v = wi >> 2;
  const int u = ug * 16 + wv * 4 + v;   // this lane's unit
  const int gl = q * 16 + wv * 4 + v;   // g_loc in pre2 block

  // stage W hi/lo slice (64 gate-rows x 512) into LDS, 16B-granule XOR swizzle
  for (int it = 0; it < 16; ++it) {
    int gg = it * 256 + tid;
    int r = gg >> 6, kq = gg & 63;
    int grow = (r & 3) * 512 + ug * 16 + (r >> 4) * 4 + ((r >> 2) & 3);
    short8 whi = *(const short8*)(Whi_g + (size_t)grow * 512 + kq * 8);
    short8 wlo = *(const short8*)(Wlo_g + (size_t)grow * 512 + kq * 8);
    int kqs = (kq & ~7) | ((kq & 7) ^ (r & 7));
    *(short8*)(WhiL + r * 512 + kqs * 8) = whi;
    *(short8*)(WloL + r * 512 + kqs * 8) = wlo;
  }

  f4 c_reg;
  {
    const float* csrc = (t0 == 0) ? c0 : c_state;
    const int brow = bg * 16 + hi4 * 4;
#pragma unroll
    for (int j = 0; j < 4; ++j) c_reg[j] = csrc[(size_t)(brow + j) * H_ + u];
  }
  int* fbase = flags + bg * 32;     // 32 per-wg flags (one 128B line)
  int* myflag = fbase + ug;
  u32x4 fv0 = (u32x4){0, 0, 0, 0}; // early-poll carry (0 => under-report => safe)
  __syncthreads();

  for (int s = t0 + 1; s <= t0 + TB; ++s) {
    // bg-local views of the parity double buffer (16 rows x 512 u32 each)
    const uint32_t* hsrc = (((s - 1) & 1) ? hP1 : hP0) + (size_t)bg * 16 * 512;
    uint32_t* hdst = ((s & 1) ? hP1 : hP0) + (size_t)bg * 16 * 512;

    // prefetch this wg's pre2 fragment — NONTEMPORAL (read-once; keep the L2
    // clean for the hot h/flag lines)
    f4 accA, accB, accC;
    {
      const f4* pp = (const f4*)(pre2 + (((size_t)(s - 1 - t0) * 32 + ug) * 4 + bg) * 1024 +
                                 gl * 16 + hi4 * 4);
      accA = __builtin_nontemporal_load(pp);
      accB = (f4){0.f, 0.f, 0.f, 0.f};
      accC = accB;
    }

    // poll all 32 sibling wg-flags; round 0 = fv0 (issued during last publish
    // drain). Flags monotonic => stale fv0 only under-reports. BOUNDED.
    {
      const int target = s - 1;
      bool ok = true;
      if (lane < 8)
        ok = (int)fv0[0] >= target && (int)fv0[1] >= target &&
             (int)fv0[2] >= target && (int)fv0[3] >= target;
      int guard = 0;
      while (!__all(ok)) {
        __builtin_amdgcn_s_sleep(2);
        ok = true;
        if (lane < 8) {
          u32x4 fv = ld_flag4_l2(fbase + lane * 4);
          ok = (int)fv[0] >= target && (int)fv[1] >= target &&
               (int)fv[2] >= target && (int)fv[3] >= target;
        }
        if (++guard > (1 << 14)) break;  // ~ms-scale worst case; no wedge
      }
    }

    // gather this wave's unit range of h_{s-1}: 8 x dwordx4 per lane (r7-verified)
    u32x4 d[8];
#pragma unroll
    for (int jj = 0; jj < 8; ++jj) {
      int local = jj * 64 + lane;
      int row = local >> 5;
      int u0v = wv * 128 + (local & 31) * 4;
      ld_x4_l2(&d[jj], hsrc + (size_t)row * 512 + u0v);
    }
    asm volatile("s_waitcnt vmcnt(0)" ::: "memory");
    __builtin_amdgcn_sched_barrier(0);
#pragma unroll
    for (int jj = 0; jj < 8; ++jj) asm volatile("" : "+v"(d[jj]));
#pragma unroll
    for (int jj = 0; jj < 8; ++jj) {
      int local = jj * 64 + lane;
      int row = local >> 5;
      int u0v = wv * 128 + (local & 31) * 4;
      int kq = u0v >> 3, half = (u0v >> 2) & 1;
      int kqs = (kq & ~7) | ((kq & 7) ^ (row & 7));
      short4_ hh, hl;
#pragma unroll
      for (int i = 0; i < 4; ++i) {
        hh[i] = (short)(d[jj][i] & 0xFFFFu);
        hl[i] = (short)(d[jj][i] >> 16);
      }
      *(short4_*)(Hh + row * 512 + kqs * 8 + half * 4) = hh;
      *(short4_*)(Hl + row * 512 + kqs * 8 + half * 4) = hl;
    }
    __syncthreads();  // staging barrier: all h staged before MFMA

    // MFMA: 3-pass bf16 hi/lo in 6 chains of 8 (r10-verified):
    // total = p + Ah*Bh + Al*Bh + Ah*Bl
    f4 accA2 = (f4){0.f, 0.f, 0.f, 0.f}, accB2 = accA2, accC2 = accA2;
    const int br = wv * 16 + wi;
#pragma unroll
    for (int ks2 = 0; ks2 < 8; ++ks2) {
#pragma unroll
      for (int p = 0; p < 2; ++p) {
        int ks = ks2 * 2 + p;
        int kq = ks * 4 + hi4;
        int kqsA = (kq & ~7) | ((kq & 7) ^ (wi & 7));
        int kqsB = (kq & ~7) | ((kq & 7) ^ (br & 7));
        short8 ah = *(const short8*)(Hh + wi * 512 + kqsA * 8);
        short8 al = *(const short8*)(Hl + wi * 512 + kqsA * 8);
        short8 bh = *(const short8*)(WhiL + br * 512 + kqsB * 8);
        short8 bl = *(const short8*)(WloL + br * 512 + kqsB * 8);
        if (p == 0) {
          accA = __builtin_amdgcn_mfma_f32_16x16x32_bf16(ah, bh, accA, 0, 0, 0);
          accB = __builtin_amdgcn_mfma_f32_16x16x32_bf16(al, bh, accB, 0, 0, 0);
          accC = __builtin_amdgcn_mfma_f32_16x16x32_bf16(ah, bl, accC, 0, 0, 0);
        } else {
          accA2 = __builtin_amdgcn_mfma_f32_16x16x32_bf16(ah, bh, accA2, 0, 0, 0);
          accB2 = __builtin_amdgcn_mfma_f32_16x16x32_bf16(al, bh, accB2, 0, 0, 0);
          accC2 = __builtin_amdgcn_mfma_f32_16x16x32_bf16(ah, bl, accC2, 0, 0, 0);
        }
      }
    }

    // gate combine (quad butterfly, verified r1-r10), pointwise
    const bool qb0 = (q & 1) != 0, qb1 = (q & 2) != 0;
    const int rowloc = hi4 * 4 + q;       // local batch row within this bg
    const int b = bg * 16 + rowloc;       // global batch row
    f4 a0;
#pragma unroll
    for (int j = 0; j < 4; ++j)
      a0[j] = (accA[j] + accA2[j]) + (accB[j] + accB2[j]) + (accC[j] + accC2[j]);
    f4 x1, s1a, s1b, x2a, x2b;
#pragma unroll
    for (int j = 0; j < 4; ++j) x1[j] = __shfl_xor(a0[j], 1);
#pragma unroll
    for (int j = 0; j < 4; ++j) {
      s1a[j] = qb0 ? x1[j] : a0[j];
      s1b[j] = qb0 ? a0[j] : x1[j];
    }
#pragma unroll
    for (int j = 0; j < 4; ++j) {
      x2a[j] = __shfl_xor(s1a[j], 2);
      x2b[j] = __shfl_xor(s1b[j], 2);
    }
    f4 cn, hn;
#pragma unroll
    for (int j = 0; j < 4; ++j) {
      float gi = qb1 ? x2a[j] : s1a[j];
      float gg = qb1 ? s1a[j] : x2a[j];
      float gf = qb1 ? x2b[j] : s1b[j];
      float go = qb1 ? s1b[j] : x2b[j];
      float iv = sigmoidf_(gi);
      float fv = sigmoidf_(gf);
      float gv = tanhf_(gg);
      float ov = sigmoidf_(go);
      float c2 = fv * c_reg[j] + iv * gv;
      cn[j] = c2;
      hn[j] = ov * tanhf_(c2);
    }
    c_reg = cn;
    float s01 = qb0 ? hn[1] : hn[0];
    float s23 = qb0 ? hn[3] : hn[2];
    float hq = qb1 ? s23 : s01;

    // publish (r5/r9 protocol at L2 scope) + early poll overlapped with drain:
    // store h -> issue flag-line loads -> vmcnt(0) -> retie -> barrier -> flag.
    uint16_t hhi = f2bf(hq);
    uint16_t hlo = f2bf(hq - bf2f(hhi));
    st_u32_l2(hdst + (size_t)rowloc * 512 + u, (uint32_t)hhi | ((uint32_t)hlo << 16));
    if (lane < 8) ld_x4_l2(&fv0, fbase + lane * 4);
    asm volatile("s_waitcnt vmcnt(0)" ::: "memory");  // h store committed at L2
    __builtin_amdgcn_sched_barrier(0);
    asm volatile("" : "+v"(fv0));
    __syncthreads();                                   // all waves drained; Hh/Hl reusable
    if (tid == 0) st_flag_l2(myflag, s);
    __builtin_nontemporal_store(hq, &out[(size_t)b * (T_ * H_) + (size_t)(s - 1) * H_ + u]);
  }

  // persist c for chunked launches
  {
    const bool qb0 = (q & 1) != 0, qb1 = (q & 2) != 0;
    const int b = bg * 16 + hi4 * 4 + q;
    float c01 = qb0 ? c_reg[1] : c_reg[0];
    float c23 = qb0 ? c_reg[3] : c_reg[2];
    c_state[(size_t)b * H_ + u] = qb1 ? c23 : c01;
  }
}

extern "C" void kernel_launch(void* const* d_in, const int* in_sizes, int n_in,
                              void* d_out, int out_size, void* d_ws, size_t ws_size,
                              hipStream_t stream) {
  (void)in_sizes; (void)n_in; (void)out_size;
  const int* x = (const int*)d_in[0];
  const float* h0 = (const float*)d_in[1];
  const float* c0 = (const float*)d_in[2];
  const float* emb = (const float*)d_in[3];
  const float* Wih = (const float*)d_in[4];
  const float* Whh = (const float*)d_in[5];
  const float* bih = (const float*)d_in[6];
  const float* bhh = (const float*)d_in[7];
  float* out = (float*)d_out;
  char* ws = (char*)d_ws;

  int* flags = (int*)ws;                          // flags[0..127], claims[192..195]
  float* c_state = (float*)(ws + 4096);           // 128 KiB
  uint32_t* hP0 = (uint32_t*)(ws + 135168);       // 128 KiB packed h (parity 0)
  uint32_t* hP1 = (uint32_t*)(ws + 266240);       // 128 KiB packed h (parity 1)
  uint16_t* Whi_g = (uint16_t*)(ws + 397312);     // 2 MiB
  uint16_t* Wlo_g = (uint16_t*)(ws + 2494464);    // 2 MiB
  float* pre2 = (float*)(ws + 4591616);           // TB*32*4*1024 fp32

  int TB = 512;
  while (TB > 2 && (size_t)4591616 + (size_t)TB * 524288 > ws_size) TB >>= 1;

  (void)hipFuncSetAttribute(reinterpret_cast<const void*>(k_lstm),
                            hipFuncAttributeMaxDynamicSharedMemorySize, 163840);

  k_prep<<<dim3(4096), dim3(256), 0, stream>>>(Whh, Whi_g, Wlo_g);
  k_init<<<dim3(128), dim3(256), 0, stream>>>(h0, hP0, flags);
  for (int t0 = 0; t0 < 512; t0 += TB) {
    k_pre<<<dim3((TB * 64 / 128) * 16), dim3(256), 0, stream>>>(x, emb, Wih, bih, bhh, pre2, t0);
    k_lstm<<<dim3(256), dim3(256), 163840, stream>>>(pre2, Whi_g, Wlo_g, c0, out, hP0, hP1,
                                                     c_state, flags, t0, TB);
  }
}

// Round 13
// 2268.448 us; speedup vs baseline: 479.5366x; 479.5366x over previous
//
#include <hip/hip_runtime.h>
#include <stdint.h>

typedef __attribute__((ext_vector_type(8))) short short8;
typedef __attribute__((ext_vector_type(4))) short short4_;
typedef __attribute__((ext_vector_type(4))) float f4;
typedef __attribute__((ext_vector_type(4))) uint32_t u32x4;

#define B_ 64
#define T_ 512
#define E_ 512
#define H_ 512
#define GH 2048  // 4*H

static __device__ __forceinline__ uint16_t f2bf(float f) {
  uint32_t u = __builtin_bit_cast(uint32_t, f);
  uint32_t r = (u + 0x7FFFu + ((u >> 16) & 1u)) >> 16;
  return (uint16_t)r;
}
static __device__ __forceinline__ float bf2f(uint16_t b) {
  return __builtin_bit_cast(float, (uint32_t)b << 16);
}
static __device__ __forceinline__ float sigmoidf_(float x) {
  return 1.0f / (1.0f + __expf(-x));
}
static __device__ __forceinline__ float tanhf_(float x) {
  float e = __expf(-2.0f * fabsf(x));
  float t = (1.0f - e) / (1.0f + e);
  return __builtin_copysignf(t, x);
}

// ---- L3-coherent (agent) access helpers: sc0 sc1 = bypass L1+L2, coherence at L3.
// Protocol (r5/r9/r10-proven): producer stores -> vmcnt(0) drain -> barrier ->
// flag; consumer: poll flags -> batched loads. Data-as-flag (no drain) is
// REFUTED on this HW (r6/r12). r8 lesson: value-consumed loads need waitcnt
// in-asm or vmcnt+sched_barrier+retie. vmcnt(N) semantics: waits oldest-first
// (m135) — used below to keep the HBM out-store out of the gather drain.
static __device__ __forceinline__ u32x4 ld_flag4_cc(const int* p) {
  u32x4 v;
  asm volatile("global_load_dwordx4 %0, %1, off sc0 sc1\n\ts_waitcnt vmcnt(0)"
               : "=v"(v) : "v"(p) : "memory");
  return v;
}
static __device__ __forceinline__ void ld_x4_cc(u32x4* d, const void* p) {
  asm volatile("global_load_dwordx4 %0, %1, off sc0 sc1" : "=v"(*d) : "v"(p));
}
static __device__ __forceinline__ void st_u32_cc(uint32_t* p, uint32_t v) {
  asm volatile("global_store_dword %0, %1, off sc0 sc1" :: "v"(p), "v"(v) : "memory");
}
static __device__ __forceinline__ void st_flag_cc(int* p, int v) {
  asm volatile("global_store_dword %0, %1, off sc0 sc1" :: "v"(p), "v"(v) : "memory");
}

// ---------------- prep: split W_hh fp32 -> bf16 hi + bf16 lo
__global__ void k_prep(const float* __restrict__ Whh, uint16_t* __restrict__ Whi_g,
                       uint16_t* __restrict__ Wlo_g) {
  int i = blockIdx.x * 256 + threadIdx.x;
  float w = Whh[i];
  uint16_t hi = f2bf(w);
  Whi_g[i] = hi;
  Wlo_g[i] = f2bf(w - bf2f(hi));
}

// ---------------- init: h0 -> packed (hi | lo<<16) parity-0 buffer; zero flags
__global__ void k_init(const float* __restrict__ h0, uint32_t* __restrict__ hP0,
                       int* __restrict__ flags) {
  int i = blockIdx.x * 256 + threadIdx.x;
  if (i < B_ * H_) {
    float v = h0[i];
    uint16_t hi = f2bf(v);
    uint16_t lo = f2bf(v - bf2f(hi));
    hP0[i] = (uint32_t)hi | ((uint32_t)lo << 16);
  }
  if (i < 128) flags[i] = 0;
}

// ---------------- pre-projection GEMM (verified r1-r10). Output: per-consumer
// blocks pre2[((t_rel*32+ug)*4+bg)*1024 + g_loc*16 + b_loc], g_loc = q*16+u_loc.
__launch_bounds__(256)
__global__ void k_pre(const int* __restrict__ x, const float* __restrict__ emb,
                      const float* __restrict__ Wih, const float* __restrict__ bih,
                      const float* __restrict__ bhh, float* __restrict__ pre2, int t0) {
  __shared__ uint16_t As[128 * 64];
  __shared__ uint16_t Bs[128 * 64];
  const int tid = threadIdx.x;
  const int tm = blockIdx.x >> 4;
  const int tn = blockIdx.x & 15;
  const int wid = tid >> 6, lane = tid & 63;
  const int wr = wid >> 1, wc = wid & 1;

  const int arow = tid >> 1;
  const int half = tid & 1;
  const int m = tm * 128 + arow;
  const int bb = m & 63;
  const int tt = t0 + (m >> 6);
  const int xid = x[bb * T_ + tt];
  const float* asrc = emb + (size_t)xid * E_ + half * 32;
  const float* bsrc = Wih + (size_t)(tn * 128 + arow) * E_ + half * 32;

  f4 acc[4][4];
#pragma unroll
  for (int a = 0; a < 4; ++a)
#pragma unroll
    for (int b = 0; b < 4; ++b) acc[a][b] = (f4){0.f, 0.f, 0.f, 0.f};

  for (int kk = 0; kk < 8; ++kk) {
    __syncthreads();
#pragma unroll
    for (int gi = 0; gi < 4; ++gi) {
      f4 a0 = *(const f4*)(asrc + kk * 64 + gi * 8);
      f4 a1 = *(const f4*)(asrc + kk * 64 + gi * 8 + 4);
      f4 b0 = *(const f4*)(bsrc + kk * 64 + gi * 8);
      f4 b1 = *(const f4*)(bsrc + kk * 64 + gi * 8 + 4);
      short8 va, vb;
#pragma unroll
      for (int j = 0; j < 4; ++j) {
        va[j] = (short)f2bf(a0[j]); va[4 + j] = (short)f2bf(a1[j]);
        vb[j] = (short)f2bf(b0[j]); vb[4 + j] = (short)f2bf(b1[j]);
      }
      int kq = half * 4 + gi;
      *(short8*)(As + arow * 64 + (kq ^ (arow & 7)) * 8) = va;
      *(short8*)(Bs + arow * 64 + (kq ^ (arow & 7)) * 8) = vb;
    }
    __syncthreads();
#pragma unroll
    for (int ks = 0; ks < 2; ++ks) {
      short8 af[4], bfr[4];
#pragma unroll
      for (int mi = 0; mi < 4; ++mi) {
        int row = wr * 64 + mi * 16 + (lane & 15);
        int kq = ks * 4 + (lane >> 4);
        af[mi] = *(const short8*)(As + row * 64 + (kq ^ (row & 7)) * 8);
      }
#pragma unroll
      for (int ni = 0; ni < 4; ++ni) {
        int row = wc * 64 + ni * 16 + (lane & 15);
        int kq = ks * 4 + (lane >> 4);
        bfr[ni] = *(const short8*)(Bs + row * 64 + (kq ^ (row & 7)) * 8);
      }
#pragma unroll
      for (int mi = 0; mi < 4; ++mi)
#pragma unroll
        for (int ni = 0; ni < 4; ++ni)
          acc[mi][ni] = __builtin_amdgcn_mfma_f32_16x16x32_bf16(af[mi], bfr[ni], acc[mi][ni], 0, 0, 0);
    }
  }
#pragma unroll
  for (int ni = 0; ni < 4; ++ni) {
    int n = tn * 128 + wc * 64 + ni * 16 + (lane & 15);
    float bias = bih[n] + bhh[n];
    int q = n >> 9, u = n & 511;
    int ug = u >> 4, uloc = u & 15;
    int gl = q * 16 + uloc;
#pragma unroll
    for (int mi = 0; mi < 4; ++mi) {
      int mrow = tm * 128 + wr * 64 + mi * 16 + (lane >> 4) * 4;
      int trel = mrow >> 6;
      int bbr = mrow & 63;
      f4 vst;
#pragma unroll
      for (int j = 0; j < 4; ++j) vst[j] = acc[mi][ni][j] + bias;
      float* dst = pre2 + (((size_t)trel * 32 + ug) * 4 + (bbr >> 4)) * 1024 + gl * 16 + (bbr & 15);
      __builtin_nontemporal_store(vst, (f4*)dst);
    }
  }
}

// ---------------- persistent recurrence: r10 baseline (proven 2041 us) with ONE
// change — the HBM out-store is deferred one step and issued AFTER the gather
// loads, drained with vmcnt(1) (oldest-first, m135): the 8 gathers complete,
// the out-store rides under the MFMA phase instead of serializing into every
// vmcnt(0). 128 wgs = 4 bg x 32 ug; 1 wg/CU. Polls bounded.
__launch_bounds__(256)
__global__ void k_lstm(const float* __restrict__ pre2, const uint16_t* __restrict__ Whi_g,
                       const uint16_t* __restrict__ Wlo_g, const float* __restrict__ c0,
                       float* __restrict__ out, uint32_t* __restrict__ hP0,
                       uint32_t* __restrict__ hP1, float* __restrict__ c_state,
                       int* __restrict__ flags, int t0, int TB) {
  extern __shared__ char smem[];
  uint16_t* WhiL = (uint16_t*)smem;              // [64][512] 64 KiB
  uint16_t* WloL = (uint16_t*)(smem + 65536);    // [64][512] 64 KiB
  uint16_t* Hh   = (uint16_t*)(smem + 131072);   // [16][512] 16 KiB
  uint16_t* Hl   = (uint16_t*)(smem + 147456);   // [16][512] 16 KiB

  const int tid = threadIdx.x;
  const int bg = blockIdx.x & 3;    // batch group (16 rows)
  const int ug = blockIdx.x >> 2;   // unit group (16 units)
  const int wv = tid >> 6, lane = tid & 63;
  const int wi = lane & 15, hi4 = lane >> 4;
  const int q = wi & 3, v = wi >> 2;
  const int u = ug * 16 + wv * 4 + v;   // this lane's unit
  const int gl = q * 16 + wv * 4 + v;   // g_loc in pre2 block

  // stage W hi/lo slice (64 gate-rows x 512) into LDS, 16B-granule XOR swizzle
  for (int it = 0; it < 16; ++it) {
    int gg = it * 256 + tid;
    int r = gg >> 6, kq = gg & 63;
    int grow = (r & 3) * 512 + ug * 16 + (r >> 4) * 4 + ((r >> 2) & 3);
    short8 whi = *(const short8*)(Whi_g + (size_t)grow * 512 + kq * 8);
    short8 wlo = *(const short8*)(Wlo_g + (size_t)grow * 512 + kq * 8);
    int kqs = (kq & ~7) | ((kq & 7) ^ (r & 7));
    *(short8*)(WhiL + r * 512 + kqs * 8) = whi;
    *(short8*)(WloL + r * 512 + kqs * 8) = wlo;
  }

  f4 c_reg;
  {
    const float* csrc = (t0 == 0) ? c0 : c_state;
    const int brow = bg * 16 + hi4 * 4;
#pragma unroll
    for (int j = 0; j < 4; ++j) c_reg[j] = csrc[(size_t)(brow + j) * H_ + u];
  }
  int* fbase = flags + bg * 32;     // 32 per-wg flags (one 128B line)
  int* myflag = fbase + ug;
  u32x4 fv0 = (u32x4){0, 0, 0, 0}; // early-poll carry (0 => under-report => safe)
  float hq_prev = 0.0f;            // deferred out value (valid from 2nd iter)
  const int rowloc = hi4 * 4 + q;  // local batch row within this bg
  const int b = bg * 16 + rowloc;  // global batch row
  __syncthreads();

  for (int s = t0 + 1; s <= t0 + TB; ++s) {
    // bg-local views of the parity double buffer (16 rows x 512 u32 each)
    const uint32_t* hsrc = (((s - 1) & 1) ? hP1 : hP0) + (size_t)bg * 16 * 512;
    uint32_t* hdst = ((s & 1) ? hP1 : hP0) + (size_t)bg * 16 * 512;

    // prefetch this wg's pre2 fragment — NONTEMPORAL (read-once stream)
    f4 accA, accB, accC;
    {
      const f4* pp = (const f4*)(pre2 + (((size_t)(s - 1 - t0) * 32 + ug) * 4 + bg) * 1024 +
                                 gl * 16 + hi4 * 4);
      accA = __builtin_nontemporal_load(pp);
      accB = (f4){0.f, 0.f, 0.f, 0.f};
      accC = accB;
    }

    // poll all 32 sibling wg-flags; round 0 = fv0 (issued during last publish
    // drain). Flags monotonic => stale fv0 only under-reports. BOUNDED.
    {
      const int target = s - 1;
      bool ok = true;
      if (lane < 8)
        ok = (int)fv0[0] >= target && (int)fv0[1] >= target &&
             (int)fv0[2] >= target && (int)fv0[3] >= target;
      int guard = 0;
      while (!__all(ok)) {
        __builtin_amdgcn_s_sleep(1);
        ok = true;
        if (lane < 8) {
          u32x4 fv = ld_flag4_cc(fbase + lane * 4);
          ok = (int)fv[0] >= target && (int)fv[1] >= target &&
               (int)fv[2] >= target && (int)fv[3] >= target;
        }
        if (++guard > (1 << 17)) break;
      }
    }

    // gather this wave's unit range of h_{s-1}: 8 x dwordx4 per lane
    // (r7/r9-verified indexing), then deferred out-store + counted drain.
    u32x4 d[8];
#pragma unroll
    for (int jj = 0; jj < 8; ++jj) {
      int local = jj * 64 + lane;
      int row = local >> 5;
      int u0v = wv * 128 + (local & 31) * 4;
      ld_x4_cc(&d[jj], hsrc + (size_t)row * 512 + u0v);
    }
    if (s > t0 + 1) {
      // deferred out store (timestep s-2, held in hq_prev): issued NEWER than
      // the gathers; vmcnt(1) waits the 8 gathers (oldest-first) and leaves
      // this HBM store in flight under the MFMA phase.
      float* optr = out + (size_t)b * (T_ * H_) + (size_t)(s - 2) * H_ + u;
      asm volatile("global_store_dword %0, %1, off" :: "v"(optr), "v"(hq_prev) : "memory");
      asm volatile("s_waitcnt vmcnt(1)" ::: "memory");
    } else {
      asm volatile("s_waitcnt vmcnt(0)" ::: "memory");
    }
    __builtin_amdgcn_sched_barrier(0);
#pragma unroll
    for (int jj = 0; jj < 8; ++jj) asm volatile("" : "+v"(d[jj]));
#pragma unroll
    for (int jj = 0; jj < 8; ++jj) {
      int local = jj * 64 + lane;
      int row = local >> 5;
      int u0v = wv * 128 + (local & 31) * 4;
      int kq = u0v >> 3, half = (u0v >> 2) & 1;
      int kqs = (kq & ~7) | ((kq & 7) ^ (row & 7));
      short4_ hh, hl;
#pragma unroll
      for (int i = 0; i < 4; ++i) {
        hh[i] = (short)(d[jj][i] & 0xFFFFu);
        hl[i] = (short)(d[jj][i] >> 16);
      }
      *(short4_*)(Hh + row * 512 + kqs * 8 + half * 4) = hh;
      *(short4_*)(Hl + row * 512 + kqs * 8 + half * 4) = hl;
    }
    __syncthreads();  // staging barrier: all h staged before MFMA

    // MFMA: 3-pass bf16 hi/lo in 6 chains of 8 (r10-verified):
    // total = p + Ah*Bh + Al*Bh + Ah*Bl
    f4 accA2 = (f4){0.f, 0.f, 0.f, 0.f}, accB2 = accA2, accC2 = accA2;
    const int br = wv * 16 + wi;
#pragma unroll
    for (int ks2 = 0; ks2 < 8; ++ks2) {
#pragma unroll
      for (int p = 0; p < 2; ++p) {
        int ks = ks2 * 2 + p;
        int kq = ks * 4 + hi4;
        int kqsA = (kq & ~7) | ((kq & 7) ^ (wi & 7));
        int kqsB = (kq & ~7) | ((kq & 7) ^ (br & 7));
        short8 ah = *(const short8*)(Hh + wi * 512 + kqsA * 8);
        short8 al = *(const short8*)(Hl + wi * 512 + kqsA * 8);
        short8 bh = *(const short8*)(WhiL + br * 512 + kqsB * 8);
        short8 bl = *(const short8*)(WloL + br * 512 + kqsB * 8);
        if (p == 0) {
          accA = __builtin_amdgcn_mfma_f32_16x16x32_bf16(ah, bh, accA, 0, 0, 0);
          accB = __builtin_amdgcn_mfma_f32_16x16x32_bf16(al, bh, accB, 0, 0, 0);
          accC = __builtin_amdgcn_mfma_f32_16x16x32_bf16(ah, bl, accC, 0, 0, 0);
        } else {
          accA2 = __builtin_amdgcn_mfma_f32_16x16x32_bf16(ah, bh, accA2, 0, 0, 0);
          accB2 = __builtin_amdgcn_mfma_f32_16x16x32_bf16(al, bh, accB2, 0, 0, 0);
          accC2 = __builtin_amdgcn_mfma_f32_16x16x32_bf16(ah, bl, accC2, 0, 0, 0);
        }
      }
    }

    // gate combine (quad butterfly, verified r1-r10), pointwise
    const bool qb0 = (q & 1) != 0, qb1 = (q & 2) != 0;
    f4 a0;
#pragma unroll
    for (int j = 0; j < 4; ++j)
      a0[j] = (accA[j] + accA2[j]) + (accB[j] + accB2[j]) + (accC[j] + accC2[j]);
    f4 x1, s1a, s1b, x2a, x2b;
#pragma unroll
    for (int j = 0; j < 4; ++j) x1[j] = __shfl_xor(a0[j], 1);
#pragma unroll
    for (int j = 0; j < 4; ++j) {
      s1a[j] = qb0 ? x1[j] : a0[j];
      s1b[j] = qb0 ? a0[j] : x1[j];
    }
#pragma unroll
    for (int j = 0; j < 4; ++j) {
      x2a[j] = __shfl_xor(s1a[j], 2);
      x2b[j] = __shfl_xor(s1b[j], 2);
    }
    f4 cn, hn;
#pragma unroll
    for (int j = 0; j < 4; ++j) {
      float gi = qb1 ? x2a[j] : s1a[j];
      float gg = qb1 ? s1a[j] : x2a[j];
      float gf = qb1 ? x2b[j] : s1b[j];
      float go = qb1 ? s1b[j] : x2b[j];
      float iv = sigmoidf_(gi);
      float fv = sigmoidf_(gf);
      float gv = tanhf_(gg);
      float ov = sigmoidf_(go);
      float c2 = fv * c_reg[j] + iv * gv;
      cn[j] = c2;
      hn[j] = ov * tanhf_(c2);
    }
    c_reg = cn;
    float s01 = qb0 ? hn[1] : hn[0];
    float s23 = qb0 ? hn[3] : hn[2];
    float hq = qb1 ? s23 : s01;

    // publish (r5/r9 protocol) + early poll overlapped with the drain:
    // store h -> issue flag-line loads -> vmcnt(0) -> retie -> barrier -> flag.
    uint16_t hhi = f2bf(hq);
    uint16_t hlo = f2bf(hq - bf2f(hhi));
    st_u32_cc(hdst + (size_t)rowloc * 512 + u, (uint32_t)hhi | ((uint32_t)hlo << 16));
    if (lane < 8) ld_x4_cc(&fv0, fbase + lane * 4);
    asm volatile("s_waitcnt vmcnt(0)" ::: "memory");  // h store committed at L3
    __builtin_amdgcn_sched_barrier(0);
    asm volatile("" : "+v"(fv0));
    __syncthreads();                                   // all waves drained; Hh/Hl reusable
    if (tid == 0) st_flag_cc(myflag, s);
    hq_prev = hq;  // out store deferred into next iteration's gather phase
  }

  // flush the final timestep's out value (index t0+TB-1)
  __builtin_nontemporal_store(hq_prev,
      &out[(size_t)b * (T_ * H_) + (size_t)(t0 + TB - 1) * H_ + u]);

  // persist c for chunked launches
  {
    const bool qb0 = (q & 1) != 0, qb1 = (q & 2) != 0;
    float c01 = qb0 ? c_reg[1] : c_reg[0];
    float c23 = qb0 ? c_reg[3] : c_reg[2];
    c_state[(size_t)b * H_ + u] = qb1 ? c23 : c01;
  }
}

extern "C" void kernel_launch(void* const* d_in, const int* in_sizes, int n_in,
                              void* d_out, int out_size, void* d_ws, size_t ws_size,
                              hipStream_t stream) {
  (void)in_sizes; (void)n_in; (void)out_size;
  const int* x = (const int*)d_in[0];
  const float* h0 = (const float*)d_in[1];
  const float* c0 = (const float*)d_in[2];
  const float* emb = (const float*)d_in[3];
  const float* Wih = (const float*)d_in[4];
  const float* Whh = (const float*)d_in[5];
  const float* bih = (const float*)d_in[6];
  const float* bhh = (const float*)d_in[7];
  float* out = (float*)d_out;
  char* ws = (char*)d_ws;

  int* flags = (int*)ws;                          // 512 B used (padded to 4 KiB)
  float* c_state = (float*)(ws + 4096);           // 128 KiB
  uint32_t* hP0 = (uint32_t*)(ws + 135168);       // 128 KiB packed h (parity 0)
  uint32_t* hP1 = (uint32_t*)(ws + 266240);       // 128 KiB packed h (parity 1)
  uint16_t* Whi_g = (uint16_t*)(ws + 397312);     // 2 MiB
  uint16_t* Wlo_g = (uint16_t*)(ws + 2494464);    // 2 MiB
  float* pre2 = (float*)(ws + 4591616);           // TB*32*4*1024 fp32

  int TB = 512;
  while (TB > 2 && (size_t)4591616 + (size_t)TB * 524288 > ws_size) TB >>= 1;

  (void)hipFuncSetAttribute(reinterpret_cast<const void*>(k_lstm),
                            hipFuncAttributeMaxDynamicSharedMemorySize, 163840);

  k_prep<<<dim3(4096), dim3(256), 0, stream>>>(Whh, Whi_g, Wlo_g);
  k_init<<<dim3(128), dim3(256), 0, stream>>>(h0, hP0, flags);
  for (int t0 = 0; t0 < 512; t0 += TB) {
    k_pre<<<dim3((TB * 64 / 128) * 16), dim3(256), 0, stream>>>(x, emb, Wih, bih, bhh, pre2, t0);
    k_lstm<<<dim3(128), dim3(256), 163840, stream>>>(pre2, Whi_g, Wlo_g, c0, out, hP0, hP1,
                                                     c_state, flags, t0, TB);
  }
}

// Round 15
// 2101.601 us; speedup vs baseline: 517.6071x; 1.0794x over previous
//
#include <hip/hip_runtime.h>
#include <stdint.h>

typedef __attribute__((ext_vector_type(8))) short short8;
typedef __attribute__((ext_vector_type(4))) short short4_;
typedef __attribute__((ext_vector_type(4))) float f4;
typedef __attribute__((ext_vector_type(4))) uint32_t u32x4;

#define B_ 64
#define T_ 512
#define E_ 512
#define H_ 512
#define GH 2048  // 4*H

static __device__ __forceinline__ uint16_t f2bf(float f) {
  uint32_t u = __builtin_bit_cast(uint32_t, f);
  uint32_t r = (u + 0x7FFFu + ((u >> 16) & 1u)) >> 16;
  return (uint16_t)r;
}
static __device__ __forceinline__ float bf2f(uint16_t b) {
  return __builtin_bit_cast(float, (uint32_t)b << 16);
}
static __device__ __forceinline__ float sigmoidf_(float x) {
  return 1.0f / (1.0f + __expf(-x));
}
static __device__ __forceinline__ float tanhf_(float x) {
  float e = __expf(-2.0f * fabsf(x));
  float t = (1.0f - e) / (1.0f + e);
  return __builtin_copysignf(t, x);
}

// ---- L3-coherent (agent) access helpers: sc0 sc1 = bypass L1+L2, coherence at L3.
// SCOPE RULE (r11/r12/r14): EVERY cross-wg handoff must be sc0sc1 on BOTH sides
// within one kernel; kernel boundaries are the only implicit flush. Protocol
// (r5/r9/r13-proven): stores -> vmcnt(0) -> barrier -> flag; consumer: poll ->
// loads. r8: value-consumed loads need waitcnt in-asm or vmcnt+sched_barrier+retie.
static __device__ __forceinline__ int ld_flag1_cc(const int* p) {
  int v;
  asm volatile("global_load_dword %0, %1, off sc0 sc1\n\ts_waitcnt vmcnt(0)"
               : "=v"(v) : "v"(p) : "memory");
  return v;
}
static __device__ __forceinline__ u32x4 ld_flag4_cc(const int* p) {
  u32x4 v;
  asm volatile("global_load_dwordx4 %0, %1, off sc0 sc1\n\ts_waitcnt vmcnt(0)"
               : "=v"(v) : "v"(p) : "memory");
  return v;
}
static __device__ __forceinline__ void ld_x4_cc(u32x4* d, const void* p) {
  asm volatile("global_load_dwordx4 %0, %1, off sc0 sc1" : "=v"(*d) : "v"(p));
}
static __device__ __forceinline__ void st_u32_cc(uint32_t* p, uint32_t v) {
  asm volatile("global_store_dword %0, %1, off sc0 sc1" :: "v"(p), "v"(v) : "memory");
}
static __device__ __forceinline__ void st_x4_cc(void* p, u32x4 v) {
  asm volatile("global_store_dwordx4 %0, %1, off sc0 sc1" :: "v"(p), "v"(v) : "memory");
}
static __device__ __forceinline__ void st_flag_cc(int* p, int v) {
  asm volatile("global_store_dword %0, %1, off sc0 sc1" :: "v"(p), "v"(v) : "memory");
}

// ---------------- prep: split W_hh fp32 -> bf16 hi + bf16 lo
__global__ void k_prep(const float* __restrict__ Whh, uint16_t* __restrict__ Whi_g,
                       uint16_t* __restrict__ Wlo_g) {
  int i = blockIdx.x * 256 + threadIdx.x;
  float w = Whh[i];
  uint16_t hi = f2bf(w);
  Whi_g[i] = hi;
  Wlo_g[i] = f2bf(w - bf2f(hi));
}

// ---------------- init: h0 -> packed parity-0 buffer; zero h-flags + pre-flags
// (plain stores OK: kernel boundary flushes before k_fused reads them)
__global__ void k_init(const float* __restrict__ h0, uint32_t* __restrict__ hP0,
                       int* __restrict__ flags) {
  int i = blockIdx.x * 256 + threadIdx.x;
  if (i < B_ * H_) {
    float v = h0[i];
    uint16_t hi = f2bf(v);
    uint16_t lo = f2bf(v - bf2f(hi));
    hP0[i] = (uint32_t)hi | ((uint32_t)lo << 16);
  }
  if (i < 5120) flags[i] = 0;  // h-flags [0..127] + pre-flags [1024..5119]
}

// ---------------- FUSED persistent kernel: 256 wgs = 128 pre-GEMM producers
// (blockIdx 0..127) + 128 recurrence wgs (128..255). 1 wg/CU capacity-exact.
// Producers: verified k_pre tile body, t-ordered tiles; pre2 stores sc0sc1 ->
// vmcnt(0) -> barrier -> tile flag (r14 fix: SAME scope both sides). Consumers:
// r13 recurrence + amortized pre-flag poll + sc0sc1 pre2 load.
__launch_bounds__(256)
__global__ void k_fused(const int* __restrict__ x, const float* __restrict__ emb,
                        const float* __restrict__ Wih, const float* __restrict__ bih,
                        const float* __restrict__ bhh, const uint16_t* __restrict__ Whi_g,
                        const uint16_t* __restrict__ Wlo_g, const float* __restrict__ c0,
                        float* __restrict__ out, uint32_t* __restrict__ hP0,
                        uint32_t* __restrict__ hP1, float* __restrict__ c_state,
                        int* __restrict__ flags, float* __restrict__ pre2,
                        int t0, int TB, int chunk1) {
  extern __shared__ char smem[];
  const int tid = threadIdx.x;
  int* preflags = flags + 1024;  // [tm][tn] = tm*16+tn, tm<TB/2, tn<16

  if (blockIdx.x < 128) {
    // ================= PRODUCER path: pre-projection GEMM (verified r1-r13) ===
    uint16_t* As = (uint16_t*)smem;            // [128][64] 16 KiB
    uint16_t* Bs = (uint16_t*)(smem + 16384);  // [128][64] 16 KiB
    const int pid = blockIdx.x;
    const int wid = tid >> 6, lane = tid & 63;
    const int wr = wid >> 1, wc = wid & 1;
    const int arow = tid >> 1;
    const int half = tid & 1;
    const int tiles_total = TB * 8;

    for (int tile = pid; tile < tiles_total; tile += 128) {  // t-ordered passes
      const int tm = tile >> 4;
      const int tn = tile & 15;
      const int m = tm * 128 + arow;
      const int bb = m & 63;
      const int tt = t0 + (m >> 6);
      const int xid = x[bb * T_ + tt];
      const float* asrc = emb + (size_t)xid * E_ + half * 32;
      const float* bsrc = Wih + (size_t)(tn * 128 + arow) * E_ + half * 32;

      f4 acc[4][4];
#pragma unroll
      for (int a = 0; a < 4; ++a)
#pragma unroll
        for (int b = 0; b < 4; ++b) acc[a][b] = (f4){0.f, 0.f, 0.f, 0.f};

      for (int kk = 0; kk < 8; ++kk) {
        __syncthreads();
#pragma unroll
        for (int gi = 0; gi < 4; ++gi) {
          f4 a0 = *(const f4*)(asrc + kk * 64 + gi * 8);
          f4 a1 = *(const f4*)(asrc + kk * 64 + gi * 8 + 4);
          f4 b0 = *(const f4*)(bsrc + kk * 64 + gi * 8);
          f4 b1 = *(const f4*)(bsrc + kk * 64 + gi * 8 + 4);
          short8 va, vb;
#pragma unroll
          for (int j = 0; j < 4; ++j) {
            va[j] = (short)f2bf(a0[j]); va[4 + j] = (short)f2bf(a1[j]);
            vb[j] = (short)f2bf(b0[j]); vb[4 + j] = (short)f2bf(b1[j]);
          }
          int kq = half * 4 + gi;
          *(short8*)(As + arow * 64 + (kq ^ (arow & 7)) * 8) = va;
          *(short8*)(Bs + arow * 64 + (kq ^ (arow & 7)) * 8) = vb;
        }
        __syncthreads();
#pragma unroll
        for (int ks = 0; ks < 2; ++ks) {
          short8 af[4], bfr[4];
#pragma unroll
          for (int mi = 0; mi < 4; ++mi) {
            int row = wr * 64 + mi * 16 + (lane & 15);
            int kq = ks * 4 + (lane >> 4);
            af[mi] = *(const short8*)(As + row * 64 + (kq ^ (row & 7)) * 8);
          }
#pragma unroll
          for (int ni = 0; ni < 4; ++ni) {
            int row = wc * 64 + ni * 16 + (lane & 15);
            int kq = ks * 4 + (lane >> 4);
            bfr[ni] = *(const short8*)(Bs + row * 64 + (kq ^ (row & 7)) * 8);
          }
#pragma unroll
          for (int mi = 0; mi < 4; ++mi)
#pragma unroll
            for (int ni = 0; ni < 4; ++ni)
              acc[mi][ni] = __builtin_amdgcn_mfma_f32_16x16x32_bf16(af[mi], bfr[ni], acc[mi][ni], 0, 0, 0);
        }
      }
#pragma unroll
      for (int ni = 0; ni < 4; ++ni) {
        int n = tn * 128 + wc * 64 + ni * 16 + (lane & 15);
        float bias = bih[n] + bhh[n];
        int q = n >> 9, u = n & 511;
        int ug = u >> 4, uloc = u & 15;
        int gl = q * 16 + uloc;
#pragma unroll
        for (int mi = 0; mi < 4; ++mi) {
          int mrow = tm * 128 + wr * 64 + mi * 16 + (lane >> 4) * 4;
          int trel = mrow >> 6;
          int bbr = mrow & 63;
          f4 vst;
#pragma unroll
          for (int j = 0; j < 4; ++j) vst[j] = acc[mi][ni][j] + bias;
          float* dst = pre2 + (((size_t)trel * 32 + ug) * 4 + (bbr >> 4)) * 1024 + gl * 16 + (bbr & 15);
          st_x4_cc(dst, __builtin_bit_cast(u32x4, vst));  // SAME scope as readers
        }
      }
      // per-tile publish: drain own stores -> barrier -> tid0 flag (proven pattern)
      asm volatile("s_waitcnt vmcnt(0)" ::: "memory");
      __syncthreads();
      if (tid == 0) st_flag_cc(preflags + tile, chunk1);
    }
    return;
  }

  // ================= RECURRENCE path (r13 byte-identical + pre-flag poll) =====
  uint16_t* WhiL = (uint16_t*)smem;              // [64][512] 64 KiB
  uint16_t* WloL = (uint16_t*)(smem + 65536);    // [64][512] 64 KiB
  uint16_t* Hh   = (uint16_t*)(smem + 131072);   // [16][512] 16 KiB
  uint16_t* Hl   = (uint16_t*)(smem + 147456);   // [16][512] 16 KiB

  const int idx2 = blockIdx.x - 128;
  const int bg = idx2 & 3;    // batch group (16 rows)
  const int ug = idx2 >> 2;   // unit group (16 units)
  const int wv = tid >> 6, lane = tid & 63;
  const int wi = lane & 15, hi4 = lane >> 4;
  const int q = wi & 3, v = wi >> 2;
  const int u = ug * 16 + wv * 4 + v;   // this lane's unit
  const int gl = q * 16 + wv * 4 + v;   // g_loc in pre2 block

  // stage W hi/lo slice (64 gate-rows x 512) into LDS, 16B-granule XOR swizzle
  for (int it = 0; it < 16; ++it) {
    int gg = it * 256 + tid;
    int r = gg >> 6, kq = gg & 63;
    int grow = (r & 3) * 512 + ug * 16 + (r >> 4) * 4 + ((r >> 2) & 3);
    short8 whi = *(const short8*)(Whi_g + (size_t)grow * 512 + kq * 8);
    short8 wlo = *(const short8*)(Wlo_g + (size_t)grow * 512 + kq * 8);
    int kqs = (kq & ~7) | ((kq & 7) ^ (r & 7));
    *(short8*)(WhiL + r * 512 + kqs * 8) = whi;
    *(short8*)(WloL + r * 512 + kqs * 8) = wlo;
  }

  f4 c_reg;
  {
    const float* csrc = (t0 == 0) ? c0 : c_state;
    const int brow = bg * 16 + hi4 * 4;
#pragma unroll
    for (int j = 0; j < 4; ++j) c_reg[j] = csrc[(size_t)(brow + j) * H_ + u];
  }
  int* fbase = flags + bg * 32;     // 32 per-wg h-flags (one 128B line)
  int* myflag = fbase + ug;
  u32x4 fv0 = (u32x4){0, 0, 0, 0}; // early-poll carry (0 => under-report => safe)
  float hq_prev = 0.0f;            // deferred out value (valid from 2nd iter)
  const int rowloc = hi4 * 4 + q;  // local batch row within this bg
  const int b = bg * 16 + rowloc;  // global batch row
  __syncthreads();

  for (int s = t0 + 1; s <= t0 + TB; ++s) {
    const int trel = s - 1 - t0;
    // bg-local views of the parity double buffer (16 rows x 512 u32 each)
    const uint32_t* hsrc = (((s - 1) & 1) ? hP1 : hP0) + (size_t)bg * 16 * 512;
    uint32_t* hdst = ((s & 1) ? hP1 : hP0) + (size_t)bg * 16 * 512;

    // amortized pre-flag poll: every 16 steps, confirm the next 8 tm x 4 tn
    // tiles (lane i: tm = trel/2 + i/4, tn = 4*(i&3) + ug/8 — covers this wg's
    // 4 gates for its unit range). BOUNDED.
    if ((trel & 15) == 0) {
      if (lane < 32) {
        const int* fp = preflags + ((trel >> 1) + (lane >> 2)) * 16 +
                        ((lane & 3) << 2) + (ug >> 3);
        int guard = 0;
        while (ld_flag1_cc(fp) < chunk1) {
          __builtin_amdgcn_s_sleep(2);
          if (++guard > (1 << 17)) break;  // bounded: failure => absmax, no wedge
        }
      }
    }

    // issue pre2 load (sc0sc1 — same scope as producer stores); drained by the
    // gather vmcnt below, retied after sched_barrier (r8-safe)
    u32x4 pv;
    {
      const float* pp = pre2 + (((size_t)trel * 32 + ug) * 4 + bg) * 1024 +
                        gl * 16 + hi4 * 4;
      ld_x4_cc(&pv, pp);
    }

    // poll all 32 sibling wg h-flags; round 0 = fv0 (issued during last publish
    // drain). Flags monotonic => stale fv0 only under-reports. BOUNDED.
    {
      const int target = s - 1;
      bool ok = true;
      if (lane < 8)
        ok = (int)fv0[0] >= target && (int)fv0[1] >= target &&
             (int)fv0[2] >= target && (int)fv0[3] >= target;
      int guard = 0;
      while (!__all(ok)) {
        __builtin_amdgcn_s_sleep(1);
        ok = true;
        if (lane < 8) {
          u32x4 fv = ld_flag4_cc(fbase + lane * 4);
          ok = (int)fv[0] >= target && (int)fv[1] >= target &&
               (int)fv[2] >= target && (int)fv[3] >= target;
        }
        if (++guard > (1 << 17)) break;
      }
    }

    // gather this wave's unit range of h_{s-1}: 8 x dwordx4 per lane
    // (r7/r9-verified indexing), then deferred out-store + counted drain.
    u32x4 d[8];
#pragma unroll
    for (int jj = 0; jj < 8; ++jj) {
      int local = jj * 64 + lane;
      int row = local >> 5;
      int u0v = wv * 128 + (local & 31) * 4;
      ld_x4_cc(&d[jj], hsrc + (size_t)row * 512 + u0v);
    }
    if (s > t0 + 1) {
      // out store (timestep s-2) issued NEWER than pre2 load + gathers;
      // vmcnt(1) waits them (oldest-first, m135), leaves the HBM store in flight.
      float* optr = out + (size_t)b * (T_ * H_) + (size_t)(s - 2) * H_ + u;
      asm volatile("global_store_dword %0, %1, off" :: "v"(optr), "v"(hq_prev) : "memory");
      asm volatile("s_waitcnt vmcnt(1)" ::: "memory");
    } else {
      asm volatile("s_waitcnt vmcnt(0)" ::: "memory");
    }
    __builtin_amdgcn_sched_barrier(0);
    asm volatile("" : "+v"(pv));
#pragma unroll
    for (int jj = 0; jj < 8; ++jj) asm volatile("" : "+v"(d[jj]));
    f4 accA = __builtin_bit_cast(f4, pv);
    f4 accB = (f4){0.f, 0.f, 0.f, 0.f}, accC = accB;
#pragma unroll
    for (int jj = 0; jj < 8; ++jj) {
      int local = jj * 64 + lane;
      int row = local >> 5;
      int u0v = wv * 128 + (local & 31) * 4;
      int kq = u0v >> 3, half = (u0v >> 2) & 1;
      int kqs = (kq & ~7) | ((kq & 7) ^ (row & 7));
      short4_ hh, hl;
#pragma unroll
      for (int i = 0; i < 4; ++i) {
        hh[i] = (short)(d[jj][i] & 0xFFFFu);
        hl[i] = (short)(d[jj][i] >> 16);
      }
      *(short4_*)(Hh + row * 512 + kqs * 8 + half * 4) = hh;
      *(short4_*)(Hl + row * 512 + kqs * 8 + half * 4) = hl;
    }
    __syncthreads();  // staging barrier: all h staged before MFMA

    // MFMA: 3-pass bf16 hi/lo in 6 chains of 8 (r10-verified)
    f4 accA2 = (f4){0.f, 0.f, 0.f, 0.f}, accB2 = accA2, accC2 = accA2;
    const int br = wv * 16 + wi;
#pragma unroll
    for (int ks2 = 0; ks2 < 8; ++ks2) {
#pragma unroll
      for (int p = 0; p < 2; ++p) {
        int ks = ks2 * 2 + p;
        int kq = ks * 4 + hi4;
        int kqsA = (kq & ~7) | ((kq & 7) ^ (wi & 7));
        int kqsB = (kq & ~7) | ((kq & 7) ^ (br & 7));
        short8 ah = *(const short8*)(Hh + wi * 512 + kqsA * 8);
        short8 al = *(const short8*)(Hl + wi * 512 + kqsA * 8);
        short8 bh = *(const short8*)(WhiL + br * 512 + kqsB * 8);
        short8 bl = *(const short8*)(WloL + br * 512 + kqsB * 8);
        if (p == 0) {
          accA = __builtin_amdgcn_mfma_f32_16x16x32_bf16(ah, bh, accA, 0, 0, 0);
          accB = __builtin_amdgcn_mfma_f32_16x16x32_bf16(al, bh, accB, 0, 0, 0);
          accC = __builtin_amdgcn_mfma_f32_16x16x32_bf16(ah, bl, accC, 0, 0, 0);
        } else {
          accA2 = __builtin_amdgcn_mfma_f32_16x16x32_bf16(ah, bh, accA2, 0, 0, 0);
          accB2 = __builtin_amdgcn_mfma_f32_16x16x32_bf16(al, bh, accB2, 0, 0, 0);
          accC2 = __builtin_amdgcn_mfma_f32_16x16x32_bf16(ah, bl, accC2, 0, 0, 0);
        }
      }
    }

    // gate combine (quad butterfly, verified r1-r13), pointwise
    const bool qb0 = (q & 1) != 0, qb1 = (q & 2) != 0;
    f4 a0;
#pragma unroll
    for (int j = 0; j < 4; ++j)
      a0[j] = (accA[j] + accA2[j]) + (accB[j] + accB2[j]) + (accC[j] + accC2[j]);
    f4 x1, s1a, s1b, x2a, x2b;
#pragma unroll
    for (int j = 0; j < 4; ++j) x1[j] = __shfl_xor(a0[j], 1);
#pragma unroll
    for (int j = 0; j < 4; ++j) {
      s1a[j] = qb0 ? x1[j] : a0[j];
      s1b[j] = qb0 ? a0[j] : x1[j];
    }
#pragma unroll
    for (int j = 0; j < 4; ++j) {
      x2a[j] = __shfl_xor(s1a[j], 2);
      x2b[j] = __shfl_xor(s1b[j], 2);
    }
    f4 cn, hn;
#pragma unroll
    for (int j = 0; j < 4; ++j) {
      float gi = qb1 ? x2a[j] : s1a[j];
      float gg = qb1 ? s1a[j] : x2a[j];
      float gf = qb1 ? x2b[j] : s1b[j];
      float go = qb1 ? s1b[j] : x2b[j];
      float iv = sigmoidf_(gi);
      float fv = sigmoidf_(gf);
      float gv = tanhf_(gg);
      float ov = sigmoidf_(go);
      float c2 = fv * c_reg[j] + iv * gv;
      cn[j] = c2;
      hn[j] = ov * tanhf_(c2);
    }
    c_reg = cn;
    float s01 = qb0 ? hn[1] : hn[0];
    float s23 = qb0 ? hn[3] : hn[2];
    float hq = qb1 ? s23 : s01;

    // publish (proven): store h -> issue flag-line loads -> vmcnt(0) -> retie ->
    // barrier -> tid0 flag; out store deferred to next iteration (r13).
    uint16_t hhi = f2bf(hq);
    uint16_t hlo = f2bf(hq - bf2f(hhi));
    st_u32_cc(hdst + (size_t)rowloc * 512 + u, (uint32_t)hhi | ((uint32_t)hlo << 16));
    if (lane < 8) ld_x4_cc(&fv0, fbase + lane * 4);
    asm volatile("s_waitcnt vmcnt(0)" ::: "memory");  // h store committed at L3
    __builtin_amdgcn_sched_barrier(0);
    asm volatile("" : "+v"(fv0));
    __syncthreads();                                   // all waves drained; Hh/Hl reusable
    if (tid == 0) st_flag_cc(myflag, s);
    hq_prev = hq;
  }

  // flush the final timestep's out value (index t0+TB-1)
  __builtin_nontemporal_store(hq_prev,
      &out[(size_t)b * (T_ * H_) + (size_t)(t0 + TB - 1) * H_ + u]);

  // persist c for chunked launches
  {
    const bool qb0 = (q & 1) != 0, qb1 = (q & 2) != 0;
    float c01 = qb0 ? c_reg[1] : c_reg[0];
    float c23 = qb0 ? c_reg[3] : c_reg[2];
    c_state[(size_t)b * H_ + u] = qb1 ? c23 : c01;
  }
}

extern "C" void kernel_launch(void* const* d_in, const int* in_sizes, int n_in,
                              void* d_out, int out_size, void* d_ws, size_t ws_size,
                              hipStream_t stream) {
  (void)in_sizes; (void)n_in; (void)out_size;
  const int* x = (const int*)d_in[0];
  const float* h0 = (const float*)d_in[1];
  const float* c0 = (const float*)d_in[2];
  const float* emb = (const float*)d_in[3];
  const float* Wih = (const float*)d_in[4];
  const float* Whh = (const float*)d_in[5];
  const float* bih = (const float*)d_in[6];
  const float* bhh = (const float*)d_in[7];
  float* out = (float*)d_out;
  char* ws = (char*)d_ws;

  int* flags = (int*)ws;                          // h-flags [0..127]; pre-flags [1024..5119]
  float* c_state = (float*)(ws + 20480);          // 128 KiB
  uint32_t* hP0 = (uint32_t*)(ws + 151552);       // 128 KiB packed h (parity 0)
  uint32_t* hP1 = (uint32_t*)(ws + 282624);       // 128 KiB packed h (parity 1)
  uint16_t* Whi_g = (uint16_t*)(ws + 413696);     // 2 MiB
  uint16_t* Wlo_g = (uint16_t*)(ws + 2510848);    // 2 MiB
  float* pre2 = (float*)(ws + 4608000);           // TB*32*4*1024 fp32

  int TB = 512;
  while (TB > 2 && (size_t)4608000 + (size_t)TB * 524288 > ws_size) TB >>= 1;

  (void)hipFuncSetAttribute(reinterpret_cast<const void*>(k_fused),
                            hipFuncAttributeMaxDynamicSharedMemorySize, 163840);

  k_prep<<<dim3(4096), dim3(256), 0, stream>>>(Whh, Whi_g, Wlo_g);
  k_init<<<dim3(128), dim3(256), 0, stream>>>(h0, hP0, flags);
  for (int t0 = 0; t0 < 512; t0 += TB) {
    int chunk1 = t0 / TB + 1;
    k_fused<<<dim3(256), dim3(256), 163840, stream>>>(x, emb, Wih, bih, bhh, Whi_g, Wlo_g,
                                                      c0, out, hP0, hP1, c_state, flags,
                                                      pre2, t0, TB, chunk1);
  }
}